// Round 6
// baseline (48.471 us; speedup 1.0000x reference)
//
#include <hip/hip_runtime.h>

// RBF interpolation weights:
//   sparse_coords: [B=4, N=256, 3] f32
//   grid_coords:   [M=65536, 3] f32
//   out:           [B, M, N] f32, normalized exp(-d2/(2*sigma^2))
//
// Write-bound: 268 MB out; device fill rate ~7.0 TB/s. R5 = 46.4 µs (72%).
// R6: phase-batched restructure. Compute all MPW m's weights first, then run
// the 6 butterfly-reduce rounds over MPW independent chains (serial depth
// 6 shfl latencies instead of 6*MPW), then burst all MPW float4 stores.

typedef float fx4 __attribute__((ext_vector_type(4)));

constexpr int B_ = 4;
constexpr int N_ = 256;
constexpr int M_ = 65536;
constexpr int MPW = 8;  // m-values per wave
// -1/(2*sigma^2) * log2(e) = -50 * 1.4426950408889634
constexpr float NEG50_LOG2E = -72.13475204444817f;

__global__ __launch_bounds__(256) void rbf_weights_kernel(
    const float* __restrict__ sparse,  // [B, N, 3]
    const float* __restrict__ grid,    // [M, 3]
    float* __restrict__ out)           // [B, M, N]
{
    const int tid  = threadIdx.x;
    const int lane = tid & 63;
    const int wave = tid >> 6;
    const int b    = blockIdx.y;
    const int m0   = (blockIdx.x * 4 + wave) * MPW;

    // Per-lane sparse points: n = 4*lane + k (contiguous -> float4 store).
    const float* sp = sparse + (size_t)b * N_ * 3 + (size_t)lane * 12;
    const fx4 p0 = *(const fx4*)(sp + 0);
    const fx4 p1 = *(const fx4*)(sp + 4);
    const fx4 p2 = *(const fx4*)(sp + 8);

    const float sx[4] = {p0.x, p0.w, p1.z, p2.y};
    const float sy[4] = {p0.y, p1.x, p1.w, p2.z};
    const float sz[4] = {p0.z, p1.y, p2.x, p2.w};
    float s2[4];
#pragma unroll
    for (int j = 0; j < 4; ++j)
        s2[j] = sx[j] * sx[j] + sy[j] * sy[j] + sz[j] * sz[j];

    // Prefetch this wave's MPW grid points (wave-uniform broadcast loads).
    float gx[MPW], gy[MPW], gz[MPW];
    const float* g = grid + (size_t)m0 * 3;
#pragma unroll
    for (int mi = 0; mi < MPW; ++mi) {
        gx[mi] = g[mi * 3 + 0];
        gy[mi] = g[mi * 3 + 1];
        gz[mi] = g[mi * 3 + 2];
    }

    // Phase 1: all weights + local sums (independent, fully pipelined).
    float w[MPW][4];
    float lsum[MPW];
#pragma unroll
    for (int mi = 0; mi < MPW; ++mi) {
        const float g2  = gx[mi] * gx[mi] + gy[mi] * gy[mi] + gz[mi] * gz[mi];
        const float ghx = -2.0f * gx[mi];
        const float ghy = -2.0f * gy[mi];
        const float ghz = -2.0f * gz[mi];

        float s = 0.0f;
#pragma unroll
        for (int j = 0; j < 4; ++j) {
            float d2 = fmaf(ghx, sx[j], fmaf(ghy, sy[j], fmaf(ghz, sz[j], g2 + s2[j])));
            const float t = fminf(d2 * NEG50_LOG2E, 0.0f);
            const float e = exp2f(t);
            w[mi][j] = e;
            s += e;
        }
        lsum[mi] = s;
    }

    // Phase 2: 6 butterfly rounds, MPW independent chains per round.
#pragma unroll
    for (int off = 32; off; off >>= 1) {
#pragma unroll
        for (int mi = 0; mi < MPW; ++mi)
            lsum[mi] += __shfl_xor(lsum[mi], off);
    }

    // Phase 3: burst the stores.
    float* outb = out + ((size_t)b * M_ + m0) * N_ + (size_t)lane * 4;
#pragma unroll
    for (int mi = 0; mi < MPW; ++mi) {
        const float inv = 1.0f / (lsum[mi] + 1e-8f);
        fx4 o4;
        o4.x = w[mi][0] * inv;
        o4.y = w[mi][1] * inv;
        o4.z = w[mi][2] * inv;
        o4.w = w[mi][3] * inv;
        *(fx4*)(outb + (size_t)mi * N_) = o4;
    }
}

extern "C" void kernel_launch(void* const* d_in, const int* in_sizes, int n_in,
                              void* d_out, int out_size, void* d_ws, size_t ws_size,
                              hipStream_t stream) {
    const float* sparse = (const float*)d_in[0];  // [4, 256, 3]
    const float* grid   = (const float*)d_in[1];  // [65536, 3]
    float* out = (float*)d_out;                   // [4, 65536, 256]

    dim3 grid_dim(M_ / (4 * MPW), B_, 1);  // 2048 x 4
    dim3 block_dim(256, 1, 1);
    rbf_weights_kernel<<<grid_dim, block_dim, 0, stream>>>(sparse, grid, out);
}